// Round 2
// baseline (3000.818 us; speedup 1.0000x reference)
//
#include <hip/hip_runtime.h>
#include <math.h>

constexpr int Nn = 64, Cc = 64, Tt = 300, Vv = 25, Ff = 64;
constexpr int TP = Tt / 2;             // 150 t-pairs per n
constexpr int CS = Tt * Vv;            // x c-stride in floats (7500)
constexpr float ALPHA = 0.2f;
constexpr float NEG_INF = -9.0e15f;

__global__ __launch_bounds__(256, 8) void gat_kernel(
    const float* __restrict__ x,    // (N,C,T,V)
    const int*   __restrict__ adj,  // (V,V)
    const float* __restrict__ W,    // (C,F)
    const float* __restrict__ a,    // (2F,1)
    float* __restrict__ out)        // (N,F,T,V)
{
    // 20,164 B total -> 8 blocks/CU
    __shared__ float hs[2][Vv][64];        // 12800 B  h[v][f], q-block XOR swizzled
    __shared__ float attT[2][Vv][28];      // 5600 B   att transposed [j][i]
    __shared__ float fpart[2][4][26][2];   // 1664 B   per-wave f1/f2 partials
    __shared__ unsigned adjm[Vv];          // 100 B

    const int tid = threadIdx.x;
    const int blk = blockIdx.x;            // n*TP + tp
    const int n = blk / TP, tp = blk - n * TP;
    const int t0 = tp * 2;

    const int wid  = tid >> 6;
    const int lane = tid & 63;
    const int ph   = lane >> 5;            // which t of the pair
    const int v    = lane & 31;            // active v < 25
    const int vL   = (v < Vv) ? v : 0;     // clamped for loads (keeps OOB lanes in-bounds)
    const int f0   = __builtin_amdgcn_readfirstlane(wid << 4);  // wave-uniform f base
    const int sw   = v & 3;                // write-side q-XOR key

    // ---- adj row bitmasks (wave 2, before any barrier; consumed after barrier 1) ----
    if (tid >= 128 && tid < 128 + Vv) {
        const int i = tid - 128;
        unsigned m = 0;
        #pragma unroll
        for (int j = 0; j < Vv; ++j) m |= (adj[i * Vv + j] > 0 ? 1u : 0u) << j;
        adjm[i] = m;
    }

    // ---- Phase B: acc[k] = sum_c x[n,c,t,v] * W[c][f0+k]; x direct global->reg ----
    float acc[16];
    #pragma unroll
    for (int k = 0; k < 16; ++k) acc[k] = 0.f;

    const float* __restrict__ xb = x + (size_t)(n * Cc * Tt + t0) * Vv;  // uniform base
    const unsigned xoff = (unsigned)(ph * Vv + vL);                      // per-lane offset
    const float* __restrict__ Wg = W + f0;                               // wave-uniform -> s_load

    #pragma unroll
    for (int c = 0; c < Cc; ++c) {
        const float xv = xb[xoff + (unsigned)(c * CS)];
        const float4 w0 = *(const float4*)(Wg + c * Ff + 0);
        const float4 w1 = *(const float4*)(Wg + c * Ff + 4);
        const float4 w2 = *(const float4*)(Wg + c * Ff + 8);
        const float4 w3 = *(const float4*)(Wg + c * Ff + 12);
        acc[0]  += xv * w0.x; acc[1]  += xv * w0.y; acc[2]  += xv * w0.z; acc[3]  += xv * w0.w;
        acc[4]  += xv * w1.x; acc[5]  += xv * w1.y; acc[6]  += xv * w1.z; acc[7]  += xv * w1.w;
        acc[8]  += xv * w2.x; acc[9]  += xv * w2.y; acc[10] += xv * w2.z; acc[11] += xv * w2.w;
        acc[12] += xv * w3.x; acc[13] += xv * w3.y; acc[14] += xv * w3.z; acc[15] += xv * w3.w;
    }

    // ---- Phase C: register-local partial dots with a1/a2 (SGPR-resident) ----
    float p1 = 0.f, p2 = 0.f;
    {
        const float* __restrict__ ag = a + f0;     // wave-uniform -> s_load
        #pragma unroll
        for (int k = 0; k < 16; ++k) {
            p1 += acc[k] * ag[k];
            p2 += acc[k] * ag[Ff + k];
        }
    }

    if (v < Vv) {
        #pragma unroll
        for (int q = 0; q < 4; ++q) {
            float4 t4;
            t4.x = acc[q * 4 + 0]; t4.y = acc[q * 4 + 1];
            t4.z = acc[q * 4 + 2]; t4.w = acc[q * 4 + 3];
            *(float4*)&hs[ph][v][f0 + 4 * (q ^ sw)] = t4;   // swizzled store
        }
        *(float2*)&fpart[ph][wid][v][0] = make_float2(p1, p2);
    }
    __syncthreads();

    // ---- Phase D: 50 lanes of wave 0 do both problems' softmax rows ----
    if (tid < 2 * Vv) {
        const int dp = (tid >= Vv) ? 1 : 0;
        const int i = tid - Vv * dp;
        float f1 = 0.f, f2 = 0.f;
        #pragma unroll
        for (int w = 0; w < 4; ++w) {
            const float2 fp = *(const float2*)&fpart[dp][w][i][0];
            f1 += fp.x; f2 += fp.y;
        }
        const unsigned m = adjm[i];
        float ev[Vv];
        float mx = -INFINITY;
        #pragma unroll
        for (int j = 0; j < Vv; ++j) {
            const float f2j = __shfl(f2, dp * Vv + j, 64);  // f2[j] lives in lane dp*25+j
            float z = f1 + f2j;
            z = (z > 0.f) ? z : ALPHA * z;                  // leaky_relu BEFORE mask
            z = ((m >> j) & 1u) ? z : NEG_INF;
            ev[j] = z; mx = fmaxf(mx, z);
        }
        float s = 0.f;
        #pragma unroll
        for (int j = 0; j < Vv; ++j) { const float e = __expf(ev[j] - mx); ev[j] = e; s += e; }
        const float inv = 1.f / s;
        #pragma unroll
        for (int j = 0; j < Vv; ++j) attT[dp][j][i] = ev[j] * inv;
    }
    __syncthreads();

    // ---- Phase E: h'[v][f-slice] = sum_j att[v][j] * h[j][f-slice] ----
    float acc2[16];
    #pragma unroll
    for (int k = 0; k < 16; ++k) acc2[k] = 0.f;
    const float* attb = &attT[ph][0][vL];
    #pragma unroll
    for (int j = 0; j < Vv; ++j) {
        const float av = attb[j * 28];                      // lane-contiguous, conflict-light
        const int K = j & 3;                                // compile-time per unrolled j
        const float4 h0 = *(const float4*)&hs[ph][j][f0 + 4 * (0 ^ K)];
        const float4 h1 = *(const float4*)&hs[ph][j][f0 + 4 * (1 ^ K)];
        const float4 h2 = *(const float4*)&hs[ph][j][f0 + 4 * (2 ^ K)];
        const float4 h3 = *(const float4*)&hs[ph][j][f0 + 4 * (3 ^ K)];
        acc2[0]  += av * h0.x; acc2[1]  += av * h0.y; acc2[2]  += av * h0.z; acc2[3]  += av * h0.w;
        acc2[4]  += av * h1.x; acc2[5]  += av * h1.y; acc2[6]  += av * h1.z; acc2[7]  += av * h1.w;
        acc2[8]  += av * h2.x; acc2[9]  += av * h2.y; acc2[10] += av * h2.z; acc2[11] += av * h2.w;
        acc2[12] += av * h3.x; acc2[13] += av * h3.y; acc2[14] += av * h3.z; acc2[15] += av * h3.w;
    }

    // ---- Phase F: elu + direct register->global writeout (200 B contiguous/store) ----
    if (v < Vv) {
        float* ob = out + ((size_t)(n * Ff + f0) * Tt + (size_t)(t0 + ph)) * Vv + v;
        #pragma unroll
        for (int k = 0; k < 16; ++k) {
            float z = acc2[k];
            z = (z > 0.f) ? z : (__expf(z) - 1.f);   // elu(alpha=1)
            ob[(size_t)k * Tt * Vv] = z;
        }
    }
}

extern "C" void kernel_launch(void* const* d_in, const int* in_sizes, int n_in,
                              void* d_out, int out_size, void* d_ws, size_t ws_size,
                              hipStream_t stream) {
    const float* x   = (const float*)d_in[0];
    const int*   adj = (const int*)d_in[1];
    const float* W   = (const float*)d_in[2];
    const float* a   = (const float*)d_in[3];
    float* out = (float*)d_out;

    dim3 grid(Nn * TP);     // 9600 blocks, 2 (n,t) problems each
    dim3 block(256);
    gat_kernel<<<grid, block, 0, stream>>>(x, adj, W, a, out);
}

// Round 3
// 753.035 us; speedup vs baseline: 3.9850x; 3.9850x over previous
//
#include <hip/hip_runtime.h>
#include <math.h>

constexpr int Nn = 64, Cc = 64, Tt = 300, Vv = 25, Ff = 64;
constexpr int TP = Tt / 2;             // 150 t-pairs per n
constexpr int CS = Tt * Vv;            // x c-stride in floats (7500)
constexpr float ALPHA = 0.2f;
constexpr float NEG_INF = -9.0e15f;

__global__ __launch_bounds__(256, 4) void gat_kernel(
    const float* __restrict__ x,    // (N,C,T,V)
    const int*   __restrict__ adj,  // (V,V)
    const float* __restrict__ W,    // (C,F)
    const float* __restrict__ a,    // (2F,1)
    float* __restrict__ out)        // (N,F,T,V)
{
    // 20,164 B total -> 8 blocks/CU (LDS-limited exactly at 8)
    __shared__ float hs[2][Vv][64];        // 12800 B  h[v][f], q-block XOR swizzled
    __shared__ float attT[2][Vv][28];      // 5600 B   att transposed [j][i]
    __shared__ float fpart[2][4][26][2];   // 1664 B   per-wave f1/f2 partials
    __shared__ unsigned adjm[Vv];          // 100 B

    const int tid = threadIdx.x;
    const int blk = blockIdx.x;            // n*TP + tp
    const int n = blk / TP, tp = blk - n * TP;
    const int t0 = tp * 2;

    const int wid  = tid >> 6;
    const int lane = tid & 63;
    const int ph   = lane >> 5;            // which t of the pair
    const int v    = lane & 31;            // active v < 25
    const int vL   = (v < Vv) ? v : 0;     // clamped for loads (keeps OOB lanes in-bounds)
    const int f0   = __builtin_amdgcn_readfirstlane(wid << 4);  // wave-uniform f base
    const int sw   = v & 3;                // write-side q-XOR key

    // ---- adj row bitmasks (wave 2, before any barrier; consumed after barrier 1) ----
    if (tid >= 128 && tid < 128 + Vv) {
        const int i = tid - 128;
        unsigned m = 0;
        #pragma unroll
        for (int j = 0; j < Vv; ++j) m |= (adj[i * Vv + j] > 0 ? 1u : 0u) << j;
        adjm[i] = m;
    }

    // ---- Phase B: acc[k] = sum_c x[n,c,t,v] * W[c][f0+k]; x direct global->reg ----
    float acc[16];
    #pragma unroll
    for (int k = 0; k < 16; ++k) acc[k] = 0.f;

    const float* __restrict__ xb = x + (size_t)(n * Cc * Tt + t0) * Vv;  // uniform base
    const unsigned xoff = (unsigned)(ph * Vv + vL);                      // per-lane offset
    const float* __restrict__ Wg = W + f0;                               // wave-uniform -> s_load

    #pragma unroll 8
    for (int c = 0; c < Cc; ++c) {
        const float xv = xb[xoff + (unsigned)(c * CS)];
        const float4 w0 = *(const float4*)(Wg + c * Ff + 0);
        const float4 w1 = *(const float4*)(Wg + c * Ff + 4);
        const float4 w2 = *(const float4*)(Wg + c * Ff + 8);
        const float4 w3 = *(const float4*)(Wg + c * Ff + 12);
        acc[0]  += xv * w0.x; acc[1]  += xv * w0.y; acc[2]  += xv * w0.z; acc[3]  += xv * w0.w;
        acc[4]  += xv * w1.x; acc[5]  += xv * w1.y; acc[6]  += xv * w1.z; acc[7]  += xv * w1.w;
        acc[8]  += xv * w2.x; acc[9]  += xv * w2.y; acc[10] += xv * w2.z; acc[11] += xv * w2.w;
        acc[12] += xv * w3.x; acc[13] += xv * w3.y; acc[14] += xv * w3.z; acc[15] += xv * w3.w;
    }

    // ---- Phase C: register-local partial dots with a1/a2 (SGPR-resident) ----
    float p1 = 0.f, p2 = 0.f;
    {
        const float* __restrict__ ag = a + f0;     // wave-uniform -> s_load
        #pragma unroll
        for (int k = 0; k < 16; ++k) {
            p1 += acc[k] * ag[k];
            p2 += acc[k] * ag[Ff + k];
        }
    }

    if (v < Vv) {
        #pragma unroll
        for (int q = 0; q < 4; ++q) {
            float4 t4;
            t4.x = acc[q * 4 + 0]; t4.y = acc[q * 4 + 1];
            t4.z = acc[q * 4 + 2]; t4.w = acc[q * 4 + 3];
            *(float4*)&hs[ph][v][f0 + 4 * (q ^ sw)] = t4;   // swizzled store
        }
        *(float2*)&fpart[ph][wid][v][0] = make_float2(p1, p2);
    }
    __syncthreads();

    // ---- Phase D: 50 lanes of wave 0 do both problems' softmax rows ----
    if (tid < 2 * Vv) {
        const int dp = (tid >= Vv) ? 1 : 0;
        const int i = tid - Vv * dp;
        float f1 = 0.f, f2 = 0.f;
        #pragma unroll
        for (int w = 0; w < 4; ++w) {
            const float2 fp = *(const float2*)&fpart[dp][w][i][0];
            f1 += fp.x; f2 += fp.y;
        }
        const unsigned m = adjm[i];
        float ev[Vv];
        float mx = -INFINITY;
        #pragma unroll
        for (int j = 0; j < Vv; ++j) {
            const float f2j = __shfl(f2, dp * Vv + j, 64);  // f2[j] lives in lane dp*25+j
            float z = f1 + f2j;
            z = (z > 0.f) ? z : ALPHA * z;                  // leaky_relu BEFORE mask
            z = ((m >> j) & 1u) ? z : NEG_INF;
            ev[j] = z; mx = fmaxf(mx, z);
        }
        float s = 0.f;
        #pragma unroll
        for (int j = 0; j < Vv; ++j) { const float e = __expf(ev[j] - mx); ev[j] = e; s += e; }
        const float inv = 1.f / s;
        #pragma unroll
        for (int j = 0; j < Vv; ++j) attT[dp][j][i] = ev[j] * inv;
    }
    __syncthreads();

    // ---- Phase E: h'[v][f-slice] = sum_j att[v][j] * h[j][f-slice] ----
    float acc2[16];
    #pragma unroll
    for (int k = 0; k < 16; ++k) acc2[k] = 0.f;
    const float* attb = &attT[ph][0][vL];
    #pragma unroll
    for (int j = 0; j < Vv; ++j) {
        const float av = attb[j * 28];                      // lane-contiguous, conflict-light
        const int K = j & 3;                                // compile-time per unrolled j
        const float4 h0 = *(const float4*)&hs[ph][j][f0 + 4 * (0 ^ K)];
        const float4 h1 = *(const float4*)&hs[ph][j][f0 + 4 * (1 ^ K)];
        const float4 h2 = *(const float4*)&hs[ph][j][f0 + 4 * (2 ^ K)];
        const float4 h3 = *(const float4*)&hs[ph][j][f0 + 4 * (3 ^ K)];
        acc2[0]  += av * h0.x; acc2[1]  += av * h0.y; acc2[2]  += av * h0.z; acc2[3]  += av * h0.w;
        acc2[4]  += av * h1.x; acc2[5]  += av * h1.y; acc2[6]  += av * h1.z; acc2[7]  += av * h1.w;
        acc2[8]  += av * h2.x; acc2[9]  += av * h2.y; acc2[10] += av * h2.z; acc2[11] += av * h2.w;
        acc2[12] += av * h3.x; acc2[13] += av * h3.y; acc2[14] += av * h3.z; acc2[15] += av * h3.w;
    }

    // ---- Phase F: elu + direct register->global writeout (200 B contiguous/store) ----
    if (v < Vv) {
        float* ob = out + ((size_t)(n * Ff + f0) * Tt + (size_t)(t0 + ph)) * Vv + v;
        #pragma unroll
        for (int k = 0; k < 16; ++k) {
            float z = acc2[k];
            z = (z > 0.f) ? z : (__expf(z) - 1.f);   // elu(alpha=1)
            ob[(size_t)k * Tt * Vv] = z;
        }
    }
}

extern "C" void kernel_launch(void* const* d_in, const int* in_sizes, int n_in,
                              void* d_out, int out_size, void* d_ws, size_t ws_size,
                              hipStream_t stream) {
    const float* x   = (const float*)d_in[0];
    const int*   adj = (const int*)d_in[1];
    const float* W   = (const float*)d_in[2];
    const float* a   = (const float*)d_in[3];
    float* out = (float*)d_out;

    dim3 grid(Nn * TP);     // 9600 blocks, 2 (n,t) problems each
    dim3 block(256);
    gat_kernel<<<grid, block, 0, stream>>>(x, adj, W, a, out);
}